// Round 3
// 919.775 us; speedup vs baseline: 1.0372x; 1.0372x over previous
//
#include <hip/hip_runtime.h>

#define TSTEPS 512
#define BATCH  1024
#define DIM    128
#define HID    128
#define FUT    128
#define BTILE  4
#define NBLOCKS (BATCH / BTILE)   // 256 -> one block per CU
#define NTHREADS 512
#define LSTR   136                // bf16 elems per LDS row (16B-aligned stride)

typedef __bf16 bf16x8 __attribute__((ext_vector_type(8)));
typedef float  f32x4  __attribute__((ext_vector_type(4)));
typedef unsigned int uint32x2 __attribute__((ext_vector_type(2)));

#define LOG2E 1.4426950408889634f

#if defined(__has_builtin)
#if __has_builtin(__builtin_amdgcn_permlane16_swap) && __has_builtin(__builtin_amdgcn_permlane32_swap)
#define HAVE_PERMSWAP 1
#endif
#endif
#ifndef HAVE_PERMSWAP
#define HAVE_PERMSWAP 0
#endif

// load 8 consecutive fp32, convert (RNE) to a bf16x8 MFMA fragment
__device__ __forceinline__ bf16x8 ldfrag(const float* __restrict__ p) {
    f32x4 a = *(const f32x4*)p;
    f32x4 b = *(const f32x4*)(p + 4);
    bf16x8 r;
    r[0] = (__bf16)a[0]; r[1] = (__bf16)a[1]; r[2] = (__bf16)a[2]; r[3] = (__bf16)a[3];
    r[4] = (__bf16)b[0]; r[5] = (__bf16)b[1]; r[6] = (__bf16)b[2]; r[7] = (__bf16)b[3];
    return r;
}

// one LSTM cell update from gate preacts {i,f,g,o}; c updated in place.
__device__ __forceinline__ float cell_update(f32x4 gv, float& c) {
    float pi = gv[0], pf = gv[1], pg = gv[2], po = gv[3];
    float ti = __builtin_amdgcn_exp2f(-LOG2E        * __builtin_fabsf(pi));
    float tf = __builtin_amdgcn_exp2f(-LOG2E        * __builtin_fabsf(pf));
    float tg = __builtin_amdgcn_exp2f(-2.0f * LOG2E * __builtin_fabsf(pg));
    float to = __builtin_amdgcn_exp2f(-LOG2E        * __builtin_fabsf(po));
    float di = 1.0f + ti, df = 1.0f + tf, dg = 1.0f + tg, dox = 1.0f + to;
    float p1 = di * df, p2 = dg * dox;
    float invP  = __builtin_amdgcn_rcpf(p1 * p2);
    float inv12 = invP * p2;   // 1/(di*df)
    float inv34 = invP * p1;   // 1/(dg*dox)
    float ig = ((pi >= 0.0f) ? 1.0f : ti) * (inv12 * df);
    float fg = ((pf >= 0.0f) ? 1.0f : tf) * (inv12 * di);
    float og = ((po >= 0.0f) ? 1.0f : to) * (inv34 * dg);
    float gg = __builtin_copysignf((1.0f - tg) * (inv34 * dox), pg);
    c = fg * c + ig * gg;
    float tc  = __builtin_amdgcn_exp2f(-2.0f * LOG2E * __builtin_fabsf(c));
    float thc = __builtin_copysignf((1.0f - tc) * __builtin_amdgcn_rcpf(1.0f + tc), c);
    return og * thc;
}

__device__ __forceinline__ float sel4(int q, float b0, float b1, float b2, float b3) {
    float lo = (q & 1) ? b1 : b0;
    float hi = (q & 1) ? b3 : b2;
    return (q & 2) ? hi : lo;
}

#if HAVE_PERMSWAP
// Direction-agnostic permlane gather. Whatever swap convention gfx950
// implements, one of the two outputs of each swap is the useful interleave,
// either in natural order or with the pair swapped (a q-index XOR that the
// caller absorbs into cell ownership via rb = q ^ f). r1_* pick which output;
// determined once at runtime by probe_permswap().
__device__ __forceinline__ float gate_gather_perm(f32x4 a, bool r1_16, bool r1_32) {
    uint32x2 s01 = __builtin_amdgcn_permlane16_swap(__float_as_uint(a[0]), __float_as_uint(a[1]), false, false);
    uint32x2 s23 = __builtin_amdgcn_permlane16_swap(__float_as_uint(a[2]), __float_as_uint(a[3]), false, false);
    unsigned lo = r1_16 ? s01[1] : s01[0];
    unsigned hi = r1_16 ? s23[1] : s23[0];
    uint32x2 fin = __builtin_amdgcn_permlane32_swap(lo, hi, false, false);
    return __uint_as_float(r1_32 ? fin[1] : fin[0]);
}
#endif

__global__ __launch_bounds__(NTHREADS, 2)
void lstm_forecast(const float* __restrict__ inp,
                   const float* __restrict__ W_ih, const float* __restrict__ W_hh,
                   const float* __restrict__ b_ih, const float* __restrict__ b_hh,
                   const float* __restrict__ W_lin, const float* __restrict__ b_lin,
                   float* __restrict__ out)
{
    // double-buffered x and h (bf16). rows 4..15 stay zero forever.
    // future phase: x_sh[0] = o-hi, x_sh[1] = o-lo.
    __shared__ __bf16 x_sh[2][16 * LSTR];
    __shared__ __bf16 h_sh[2][16 * LSTR];

    const int tid  = threadIdx.x;
    const int lane = tid & 63;
    const int wave = tid >> 6;      // 0..7
    const int q    = lane >> 4;     // 0..3
    const int m    = lane & 15;     // 0..15
    const int bo   = blockIdx.x * BTILE;

    for (int i = tid; i < 16 * LSTR; i += NTHREADS) {
        x_sh[0][i] = (__bf16)0.0f;
        x_sh[1][i] = (__bf16)0.0f;
        h_sh[0][i] = (__bf16)0.0f;
        h_sh[1][i] = (__bf16)0.0f;
    }

    // ---- runtime probe of the permlane-swap convention ----
    bool use_perm = false, r1_16 = false, r1_32 = false;
    int  fmap = 0;
#if HAVE_PERMSWAP
    {
        unsigned lid = (unsigned)lane;
        uint32x2 t16 = __builtin_amdgcn_permlane16_swap(lid, lid + 1000u, false, false);
        unsigned v16 = (unsigned)__builtin_amdgcn_readlane((int)t16[0], 0);
        uint32x2 t32 = __builtin_amdgcn_permlane32_swap(lid, lid + 1000u, false, false);
        unsigned v32 = (unsigned)__builtin_amdgcn_readlane((int)t32[0], 0);
        bool ok16 = (v16 == 0u) || (v16 == 16u) || (v16 == 1000u) || (v16 == 1016u);
        bool ok32 = (v32 == 0u) || (v32 == 32u) || (v32 == 1000u) || (v32 == 1032u);
        r1_16 = (v16 == 16u) || (v16 == 1016u);   // useful interleave in output[1]
        r1_32 = (v32 == 32u) || (v32 == 1032u);
        bool fl16 = (v16 >= 1000u);               // pair order swapped -> q ^ 1
        bool fl32 = (v32 >= 1000u);               // halves swapped     -> q ^ 2
        use_perm = ok16 && ok32;
        fmap = (fl16 ? 1 : 0) | (fl32 ? 2 : 0);
    }
#endif

    // ---- persistent weight fragments in VGPRs ----
    // wave w owns, per gate g, gate columns n = g*128 + 16w + m
    bf16x8 wih[4][4], whh[4][4], wlin[4];
    float  bias_g[4];
    #pragma unroll
    for (int g = 0; g < 4; ++g) {
        const int n = g * HID + wave * 16 + m;
        bias_g[g] = b_ih[n] + b_hh[n];
        #pragma unroll
        for (int kt = 0; kt < 4; ++kt) {
            wih[g][kt] = ldfrag(W_ih + (size_t)n * DIM + kt * 32 + q * 8);
            whh[g][kt] = ldfrag(W_hh + (size_t)n * HID + kt * 32 + q * 8);
        }
    }
    const int   nl     = wave * 16 + m;
    const float bias_l = b_lin[nl];
    #pragma unroll
    for (int kt = 0; kt < 4; ++kt)
        wlin[kt] = ldfrag(W_lin + (size_t)nl * HID + kt * 32 + q * 8);

    // cell ownership (intra-wave): lane owns (batch row rb, hidden col jj).
    // With the permlane gather, lane (q,m) receives gates of row (q ^ fmap),
    // so ownership shifts accordingly (bijective, consistent both phases).
    const int rb = use_perm ? (q ^ fmap) : q;
    const int jj = wave * 16 + m;
    float creg = 0.0f;

    const int lk    = m * LSTR + q * 8;     // A-frag base offset (bf16 elems)
    const int paddr = (lane & 15) << 2;     // ds_bpermute byte addr (src lane = m)

    // x staging ownership: thread loads inp[t][bo+cr][cc]
    const int cr = tid >> 7, cc = tid & 127;
    const float* xptr = inp + (size_t)(bo + cr) * DIM + cc;
    const size_t XS = (size_t)BATCH * DIM;

    // two register banks of 8 timesteps each
    float bank0[8], bank1[8];
    #pragma unroll
    for (int k = 0; k < 8; ++k) {
        bank0[k] = xptr[(size_t)k * XS];
        bank1[k] = xptr[(size_t)(8 + k) * XS];
    }

    __syncthreads();

    // ================= main recurrence =================
    for (int tb = 0; tb < TSTEPS; tb += 16) {
        #pragma unroll
        for (int j = 0; j < 16; ++j) {
            const int p = j & 1;                       // tb is even
            float xv = (j < 8) ? bank0[j] : bank1[j - 8];
            x_sh[p][cr * LSTR + cc] = (__bf16)xv;      // commit x_t
            __syncthreads();                           // x_t, h_t visible

            // refill the just-drained bank (issued right after barrier:
            // a full step of slack before the next vmcnt(0) drain)
            if (j == 7) {
                if (tb + 16 < TSTEPS) {
                    #pragma unroll
                    for (int k = 0; k < 8; ++k)
                        bank0[k] = xptr[(size_t)(tb + 16 + k) * XS];
                }
            }
            if (j == 15) {
                if (tb + 24 < TSTEPS) {
                    #pragma unroll
                    for (int k = 0; k < 8; ++k)
                        bank1[k] = xptr[(size_t)(tb + 24 + k) * XS];
                }
            }

            f32x4 acc[4];
            #pragma unroll
            for (int g = 0; g < 4; ++g)
                acc[g] = (f32x4){bias_g[g], bias_g[g], bias_g[g], bias_g[g]};
            #pragma unroll
            for (int kt = 0; kt < 4; ++kt) {
                bf16x8 ax = *(const bf16x8*)&x_sh[p][lk + kt * 32];
                bf16x8 ah = *(const bf16x8*)&h_sh[p][lk + kt * 32];
                #pragma unroll
                for (int g = 0; g < 4; ++g) {
                    acc[g] = __builtin_amdgcn_mfma_f32_16x16x32_bf16(ax, wih[g][kt], acc[g], 0, 0, 0);
                    acc[g] = __builtin_amdgcn_mfma_f32_16x16x32_bf16(ah, whh[g][kt], acc[g], 0, 0, 0);
                }
            }

            // gate redistribution: dst lane gets all 4 gates of its cell
            f32x4 gv;
#if HAVE_PERMSWAP
            if (use_perm) {
                #pragma unroll
                for (int g = 0; g < 4; ++g)
                    gv[g] = gate_gather_perm(acc[g], r1_16, r1_32);
            } else
#endif
            {
                #pragma unroll
                for (int g = 0; g < 4; ++g) {
                    float b0 = __int_as_float(__builtin_amdgcn_ds_bpermute(paddr, __float_as_int(acc[g][0])));
                    float b1 = __int_as_float(__builtin_amdgcn_ds_bpermute(paddr, __float_as_int(acc[g][1])));
                    float b2 = __int_as_float(__builtin_amdgcn_ds_bpermute(paddr, __float_as_int(acc[g][2])));
                    float b3 = __int_as_float(__builtin_amdgcn_ds_bpermute(paddr, __float_as_int(acc[g][3])));
                    gv[g] = sel4(q, b0, b1, b2, b3);
                }
            }

            float h = cell_update(gv, creg);
            h_sh[p ^ 1][rb * LSTR + jj] = (__bf16)h;   // for step t+1
        }
    }

    // ================= future phase =================
    int ph = 0;   // h_512 is in h_sh[0]
    for (int tf = 0; tf <= FUT; ++tf) {
        __syncthreads();   // S1: h_sh[ph] visible
        f32x4 accl = (f32x4){bias_l, bias_l, bias_l, bias_l};
        #pragma unroll
        for (int kt = 0; kt < 4; ++kt) {
            bf16x8 ah = *(const bf16x8*)&h_sh[ph][lk + kt * 32];
            accl = __builtin_amdgcn_mfma_f32_16x16x32_bf16(ah, wlin[kt], accl, 0, 0, 0);
        }
        if (q == 0) {
            #pragma unroll
            for (int r = 0; r < 4; ++r) {
                float o = accl[r];
                out[(size_t)tf * BATCH * HID + (size_t)(bo + r) * HID + nl] = o;
                if (tf < FUT) {
                    __bf16 hi = (__bf16)o;
                    x_sh[0][r * LSTR + nl] = hi;
                    x_sh[1][r * LSTR + nl] = (__bf16)(o - (float)hi);
                }
            }
        }
        if (tf == FUT) break;
        __syncthreads();   // S2: o-feedback visible

        f32x4 acc[4];
        #pragma unroll
        for (int g = 0; g < 4; ++g)
            acc[g] = (f32x4){bias_g[g], bias_g[g], bias_g[g], bias_g[g]};
        #pragma unroll
        for (int kt = 0; kt < 4; ++kt) {
            bf16x8 axh = *(const bf16x8*)&x_sh[0][lk + kt * 32];
            bf16x8 axl = *(const bf16x8*)&x_sh[1][lk + kt * 32];
            bf16x8 ah  = *(const bf16x8*)&h_sh[ph][lk + kt * 32];
            #pragma unroll
            for (int g = 0; g < 4; ++g) {
                acc[g] = __builtin_amdgcn_mfma_f32_16x16x32_bf16(axh, wih[g][kt], acc[g], 0, 0, 0);
                acc[g] = __builtin_amdgcn_mfma_f32_16x16x32_bf16(axl, wih[g][kt], acc[g], 0, 0, 0);
                acc[g] = __builtin_amdgcn_mfma_f32_16x16x32_bf16(ah,  whh[g][kt], acc[g], 0, 0, 0);
            }
        }
        f32x4 gv;
#if HAVE_PERMSWAP
        if (use_perm) {
            #pragma unroll
            for (int g = 0; g < 4; ++g)
                gv[g] = gate_gather_perm(acc[g], r1_16, r1_32);
        } else
#endif
        {
            #pragma unroll
            for (int g = 0; g < 4; ++g) {
                float b0 = __int_as_float(__builtin_amdgcn_ds_bpermute(paddr, __float_as_int(acc[g][0])));
                float b1 = __int_as_float(__builtin_amdgcn_ds_bpermute(paddr, __float_as_int(acc[g][1])));
                float b2 = __int_as_float(__builtin_amdgcn_ds_bpermute(paddr, __float_as_int(acc[g][2])));
                float b3 = __int_as_float(__builtin_amdgcn_ds_bpermute(paddr, __float_as_int(acc[g][3])));
                gv[g] = sel4(q, b0, b1, b2, b3);
            }
        }

        float h = cell_update(gv, creg);
        h_sh[ph ^ 1][rb * LSTR + jj] = (__bf16)h;
        ph ^= 1;
    }
}

extern "C" void kernel_launch(void* const* d_in, const int* in_sizes, int n_in,
                              void* d_out, int out_size, void* d_ws, size_t ws_size,
                              hipStream_t stream) {
    const float* inp   = (const float*)d_in[0];
    const float* W_ih  = (const float*)d_in[1];
    const float* W_hh  = (const float*)d_in[2];
    const float* b_ih  = (const float*)d_in[3];
    const float* b_hh  = (const float*)d_in[4];
    const float* W_lin = (const float*)d_in[5];
    const float* b_lin = (const float*)d_in[6];
    float* out = (float*)d_out;

    hipLaunchKernelGGL(lstm_forecast, dim3(NBLOCKS), dim3(NTHREADS), 0, stream,
                       inp, W_ih, W_hh, b_ih, b_hh, W_lin, b_lin, out);
}

// Round 4
// 845.335 us; speedup vs baseline: 1.1285x; 1.0881x over previous
//
#include <hip/hip_runtime.h>

#define TSTEPS 512
#define BATCH  1024
#define DIM    128
#define HID    128
#define FUT    128
#define BTILE  4
#define NBLOCKS (BATCH / BTILE)   // 256 -> one block per CU
#define NTHREADS 512
#define LSTR   136                // bf16 elems per LDS row (16B-aligned stride)

typedef __bf16 bf16x8 __attribute__((ext_vector_type(8)));
typedef float  f32x4  __attribute__((ext_vector_type(4)));
typedef unsigned int uint32x2 __attribute__((ext_vector_type(2)));

#define LOG2E 1.4426950408889634f

#if defined(__has_builtin)
#if __has_builtin(__builtin_amdgcn_permlane16_swap) && __has_builtin(__builtin_amdgcn_permlane32_swap)
#define HAVE_PERMSWAP 1
#endif
#endif
#ifndef HAVE_PERMSWAP
#define HAVE_PERMSWAP 0
#endif

// load 8 consecutive fp32, convert (RNE) to a bf16x8 MFMA fragment
__device__ __forceinline__ bf16x8 ldfrag(const float* __restrict__ p) {
    f32x4 a = *(const f32x4*)p;
    f32x4 b = *(const f32x4*)(p + 4);
    bf16x8 r;
    r[0] = (__bf16)a[0]; r[1] = (__bf16)a[1]; r[2] = (__bf16)a[2]; r[3] = (__bf16)a[3];
    r[4] = (__bf16)b[0]; r[5] = (__bf16)b[1]; r[6] = (__bf16)b[2]; r[7] = (__bf16)b[3];
    return r;
}

// one LSTM cell update from gate preacts {i,f,g,o}; c updated in place.
__device__ __forceinline__ float cell_update(f32x4 gv, float& c) {
    float pi = gv[0], pf = gv[1], pg = gv[2], po = gv[3];
    float ti = __builtin_amdgcn_exp2f(-LOG2E        * __builtin_fabsf(pi));
    float tf = __builtin_amdgcn_exp2f(-LOG2E        * __builtin_fabsf(pf));
    float tg = __builtin_amdgcn_exp2f(-2.0f * LOG2E * __builtin_fabsf(pg));
    float to = __builtin_amdgcn_exp2f(-LOG2E        * __builtin_fabsf(po));
    float di = 1.0f + ti, df = 1.0f + tf, dg = 1.0f + tg, dox = 1.0f + to;
    float p1 = di * df, p2 = dg * dox;
    float invP  = __builtin_amdgcn_rcpf(p1 * p2);
    float inv12 = invP * p2;   // 1/(di*df)
    float inv34 = invP * p1;   // 1/(dg*dox)
    float ig = ((pi >= 0.0f) ? 1.0f : ti) * (inv12 * df);
    float fg = ((pf >= 0.0f) ? 1.0f : tf) * (inv12 * di);
    float og = ((po >= 0.0f) ? 1.0f : to) * (inv34 * dg);
    float gg = __builtin_copysignf((1.0f - tg) * (inv34 * dox), pg);
    c = fg * c + ig * gg;
    float tc  = __builtin_amdgcn_exp2f(-2.0f * LOG2E * __builtin_fabsf(c));
    float thc = __builtin_copysignf((1.0f - tc) * __builtin_amdgcn_rcpf(1.0f + tc), c);
    return og * thc;
}

__device__ __forceinline__ float sel4(int q, float b0, float b1, float b2, float b3) {
    float lo = (q & 1) ? b1 : b0;
    float hi = (q & 1) ? b3 : b2;
    return (q & 2) ? hi : lo;
}

#if HAVE_PERMSWAP
// Direction-agnostic permlane gather (probed at runtime). Lane (q,m) ends up
// with acc row (q ^ fmap); ownership absorbs the XOR via rb = q ^ fmap.
__device__ __forceinline__ float gate_gather_perm(f32x4 a, bool r1_16, bool r1_32) {
    uint32x2 s01 = __builtin_amdgcn_permlane16_swap(__float_as_uint(a[0]), __float_as_uint(a[1]), false, false);
    uint32x2 s23 = __builtin_amdgcn_permlane16_swap(__float_as_uint(a[2]), __float_as_uint(a[3]), false, false);
    unsigned lo = r1_16 ? s01[1] : s01[0];
    unsigned hi = r1_16 ? s23[1] : s23[0];
    uint32x2 fin = __builtin_amdgcn_permlane32_swap(lo, hi, false, false);
    return __uint_as_float(r1_32 ? fin[1] : fin[0]);
}
#endif

__global__ __launch_bounds__(NTHREADS, 2)
void lstm_forecast(const float* __restrict__ inp,
                   const float* __restrict__ W_ih, const float* __restrict__ W_hh,
                   const float* __restrict__ b_ih, const float* __restrict__ b_hh,
                   const float* __restrict__ W_lin, const float* __restrict__ b_lin,
                   float* __restrict__ out)
{
    // h: double-buffered (bf16), rows 4..15 stay zero.
    // x_sh[0] in main phase: 16-row tile = 4 timesteps x 4 batch rows
    //   (row = 4*(b^fmap) + t'), restaged once per 4 steps.
    // future phase: x_sh[0] = o-hi, x_sh[1] = o-lo (rows 4..15 re-zeroed).
    __shared__ __bf16 x_sh[2][16 * LSTR];
    __shared__ __bf16 h_sh[2][16 * LSTR];

    const int tid  = threadIdx.x;
    const int lane = tid & 63;
    const int wave = tid >> 6;      // 0..7
    const int q    = lane >> 4;     // 0..3
    const int m    = lane & 15;     // 0..15
    const int bo   = blockIdx.x * BTILE;

    for (int i = tid; i < 16 * LSTR; i += NTHREADS) {
        x_sh[0][i] = (__bf16)0.0f;
        x_sh[1][i] = (__bf16)0.0f;
        h_sh[0][i] = (__bf16)0.0f;
        h_sh[1][i] = (__bf16)0.0f;
    }

    // ---- runtime probe of the permlane-swap convention ----
    bool use_perm = false, r1_16 = false, r1_32 = false;
    int  fmap = 0;
#if HAVE_PERMSWAP
    {
        unsigned lid = (unsigned)lane;
        uint32x2 t16 = __builtin_amdgcn_permlane16_swap(lid, lid + 1000u, false, false);
        unsigned v16 = (unsigned)__builtin_amdgcn_readlane((int)t16[0], 0);
        uint32x2 t32 = __builtin_amdgcn_permlane32_swap(lid, lid + 1000u, false, false);
        unsigned v32 = (unsigned)__builtin_amdgcn_readlane((int)t32[0], 0);
        bool ok16 = (v16 == 0u) || (v16 == 16u) || (v16 == 1000u) || (v16 == 1016u);
        bool ok32 = (v32 == 0u) || (v32 == 32u) || (v32 == 1000u) || (v32 == 1032u);
        r1_16 = (v16 == 16u) || (v16 == 1016u);
        r1_32 = (v32 == 32u) || (v32 == 1032u);
        bool fl16 = (v16 >= 1000u);
        bool fl32 = (v32 >= 1000u);
        use_perm = ok16 && ok32;
        fmap = (fl16 ? 1 : 0) | (fl32 ? 2 : 0);
    }
#endif

    // ---- persistent weight fragments in VGPRs ----
    bf16x8 wih[4][4], whh[4][4], wlin[4];
    float  bias_g[4];
    #pragma unroll
    for (int g = 0; g < 4; ++g) {
        const int n = g * HID + wave * 16 + m;
        bias_g[g] = b_ih[n] + b_hh[n];
        #pragma unroll
        for (int kt = 0; kt < 4; ++kt) {
            wih[g][kt] = ldfrag(W_ih + (size_t)n * DIM + kt * 32 + q * 8);
            whh[g][kt] = ldfrag(W_hh + (size_t)n * HID + kt * 32 + q * 8);
        }
    }
    const int   nl     = wave * 16 + m;
    const float bias_l = b_lin[nl];
    #pragma unroll
    for (int kt = 0; kt < 4; ++kt)
        wlin[kt] = ldfrag(W_lin + (size_t)nl * HID + kt * 32 + q * 8);

    // cell ownership: lane (q,m) owns (batch row rb, hidden col jj)
    const int rb = use_perm ? (q ^ fmap) : q;
    const int jj = wave * 16 + m;
    float creg = 0.0f;

    const int lk    = m * LSTR + q * 8;     // A-frag base offset (bf16 elems)
    const int paddr = (lane & 15) << 2;     // ds_bpermute byte addr

    // x staging ownership: thread loads inp[t][bo+cr][cc]
    const int cr = tid >> 7, cc = tid & 127;
    const float* xptr = inp + (size_t)(bo + cr) * DIM + cc;
    const size_t XS = (size_t)BATCH * DIM;
    // x-tile row base for this thread's batch row (XOR matches gather remap)
    const int xrowb = 4 * (use_perm ? (cr ^ fmap) : cr);

    // two register banks of 8 timesteps each
    float bank0[8], bank1[8];
    #pragma unroll
    for (int k = 0; k < 8; ++k) {
        bank0[k] = xptr[(size_t)k * XS];
        bank1[k] = xptr[(size_t)(8 + k) * XS];
    }

    __syncthreads();

    // per-4-step group: xacc[g] reg j = bias + xW for (batch rb, step t'=j)
    f32x4 xacc[4];

    // ================= main recurrence =================
    for (int tb = 0; tb < TSTEPS; tb += 16) {
        #pragma unroll
        for (int j = 0; j < 16; ++j) {
            const int p = j & 1;
            if ((j & 3) == 0) {
                // stage 16-row x tile for steps tb+j .. tb+j+3
                #pragma unroll
                for (int k = 0; k < 4; ++k) {
                    float xv = ((j + k) < 8) ? bank0[j + k] : bank1[j + k - 8];
                    x_sh[0][(xrowb + k) * LSTR + cc] = (__bf16)xv;
                }
            }
            __syncthreads();   // x tile (group start) + h_t visible

            if (j == 7) {
                if (tb + 16 < TSTEPS) {
                    #pragma unroll
                    for (int k = 0; k < 8; ++k)
                        bank0[k] = xptr[(size_t)(tb + 16 + k) * XS];
                }
            }
            if (j == 15) {
                if (tb + 24 < TSTEPS) {
                    #pragma unroll
                    for (int k = 0; k < 8; ++k)
                        bank1[k] = xptr[(size_t)(tb + 24 + k) * XS];
                }
            }

            if ((j & 3) == 0) {
                // group-start: precompute bias + x@W_ih for 4 steps at
                // full 16-row MFMA utilization (amortized 4 MFMA/step)
                #pragma unroll
                for (int g = 0; g < 4; ++g)
                    xacc[g] = (f32x4){bias_g[g], bias_g[g], bias_g[g], bias_g[g]};
                #pragma unroll
                for (int kt = 0; kt < 4; ++kt) {
                    bf16x8 ax = *(const bf16x8*)&x_sh[0][lk + kt * 32];
                    #pragma unroll
                    for (int g = 0; g < 4; ++g)
                        xacc[g] = __builtin_amdgcn_mfma_f32_16x16x32_bf16(ax, wih[g][kt], xacc[g], 0, 0, 0);
                }
            }

            // recurrent part: h @ W_hh only (16 MFMAs, chain of 4)
            f32x4 hacc[4];
            #pragma unroll
            for (int g = 0; g < 4; ++g)
                hacc[g] = (f32x4){0.0f, 0.0f, 0.0f, 0.0f};
            #pragma unroll
            for (int kt = 0; kt < 4; ++kt) {
                bf16x8 ah = *(const bf16x8*)&h_sh[p][lk + kt * 32];
                #pragma unroll
                for (int g = 0; g < 4; ++g)
                    hacc[g] = __builtin_amdgcn_mfma_f32_16x16x32_bf16(ah, whh[g][kt], hacc[g], 0, 0, 0);
            }

            f32x4 gv;
#if HAVE_PERMSWAP
            if (use_perm) {
                #pragma unroll
                for (int g = 0; g < 4; ++g)
                    gv[g] = gate_gather_perm(hacc[g], r1_16, r1_32) + xacc[g][j & 3];
            } else
#endif
            {
                #pragma unroll
                for (int g = 0; g < 4; ++g) {
                    float b0 = __int_as_float(__builtin_amdgcn_ds_bpermute(paddr, __float_as_int(hacc[g][0])));
                    float b1 = __int_as_float(__builtin_amdgcn_ds_bpermute(paddr, __float_as_int(hacc[g][1])));
                    float b2 = __int_as_float(__builtin_amdgcn_ds_bpermute(paddr, __float_as_int(hacc[g][2])));
                    float b3 = __int_as_float(__builtin_amdgcn_ds_bpermute(paddr, __float_as_int(hacc[g][3])));
                    gv[g] = sel4(q, b0, b1, b2, b3) + xacc[g][j & 3];
                }
            }

            float h = cell_update(gv, creg);
            h_sh[p ^ 1][rb * LSTR + jj] = (__bf16)h;   // for step t+1
        }
    }

    // re-zero x tile rows 4..15 (stale x data) before the future phase,
    // which zero-pads batch rows 4..15. x_sh[1] was untouched: still zero.
    for (int i = tid; i < 16 * LSTR; i += NTHREADS)
        if (i >= 4 * LSTR) x_sh[0][i] = (__bf16)0.0f;

    // ================= future phase =================
    int ph = 0;   // h_512 is in h_sh[0]
    for (int tf = 0; tf <= FUT; ++tf) {
        __syncthreads();   // S1: h_sh[ph] (and re-zeroed x rows) visible
        f32x4 accl = (f32x4){bias_l, bias_l, bias_l, bias_l};
        #pragma unroll
        for (int kt = 0; kt < 4; ++kt) {
            bf16x8 ah = *(const bf16x8*)&h_sh[ph][lk + kt * 32];
            accl = __builtin_amdgcn_mfma_f32_16x16x32_bf16(ah, wlin[kt], accl, 0, 0, 0);
        }
        if (q == 0) {
            #pragma unroll
            for (int r = 0; r < 4; ++r) {
                float o = accl[r];
                out[(size_t)tf * BATCH * HID + (size_t)(bo + r) * HID + nl] = o;
                if (tf < FUT) {
                    __bf16 hi = (__bf16)o;
                    x_sh[0][r * LSTR + nl] = hi;
                    x_sh[1][r * LSTR + nl] = (__bf16)(o - (float)hi);
                }
            }
        }
        if (tf == FUT) break;
        __syncthreads();   // S2: o-feedback visible

        f32x4 acc[4];
        #pragma unroll
        for (int g = 0; g < 4; ++g)
            acc[g] = (f32x4){bias_g[g], bias_g[g], bias_g[g], bias_g[g]};
        #pragma unroll
        for (int kt = 0; kt < 4; ++kt) {
            bf16x8 axh = *(const bf16x8*)&x_sh[0][lk + kt * 32];
            bf16x8 axl = *(const bf16x8*)&x_sh[1][lk + kt * 32];
            bf16x8 ah  = *(const bf16x8*)&h_sh[ph][lk + kt * 32];
            #pragma unroll
            for (int g = 0; g < 4; ++g) {
                acc[g] = __builtin_amdgcn_mfma_f32_16x16x32_bf16(axh, wih[g][kt], acc[g], 0, 0, 0);
                acc[g] = __builtin_amdgcn_mfma_f32_16x16x32_bf16(axl, wih[g][kt], acc[g], 0, 0, 0);
                acc[g] = __builtin_amdgcn_mfma_f32_16x16x32_bf16(ah,  whh[g][kt], acc[g], 0, 0, 0);
            }
        }
        f32x4 gv;
#if HAVE_PERMSWAP
        if (use_perm) {
            #pragma unroll
            for (int g = 0; g < 4; ++g)
                gv[g] = gate_gather_perm(acc[g], r1_16, r1_32);
        } else
#endif
        {
            #pragma unroll
            for (int g = 0; g < 4; ++g) {
                float b0 = __int_as_float(__builtin_amdgcn_ds_bpermute(paddr, __float_as_int(acc[g][0])));
                float b1 = __int_as_float(__builtin_amdgcn_ds_bpermute(paddr, __float_as_int(acc[g][1])));
                float b2 = __int_as_float(__builtin_amdgcn_ds_bpermute(paddr, __float_as_int(acc[g][2])));
                float b3 = __int_as_float(__builtin_amdgcn_ds_bpermute(paddr, __float_as_int(acc[g][3])));
                gv[g] = sel4(q, b0, b1, b2, b3);
            }
        }

        float h = cell_update(gv, creg);
        h_sh[ph ^ 1][rb * LSTR + jj] = (__bf16)h;
        ph ^= 1;
    }
}

extern "C" void kernel_launch(void* const* d_in, const int* in_sizes, int n_in,
                              void* d_out, int out_size, void* d_ws, size_t ws_size,
                              hipStream_t stream) {
    const float* inp   = (const float*)d_in[0];
    const float* W_ih  = (const float*)d_in[1];
    const float* W_hh  = (const float*)d_in[2];
    const float* b_ih  = (const float*)d_in[3];
    const float* b_hh  = (const float*)d_in[4];
    const float* W_lin = (const float*)d_in[5];
    const float* b_lin = (const float*)d_in[6];
    float* out = (float*)d_out;

    hipLaunchKernelGGL(lstm_forecast, dim3(NBLOCKS), dim3(NTHREADS), 0, stream,
                       inp, W_ih, W_hh, b_ih, b_hh, W_lin, b_lin, out);
}

// Round 13
// 810.578 us; speedup vs baseline: 1.1769x; 1.0429x over previous
//
#include <hip/hip_runtime.h>

#define TSTEPS 512
#define BATCH  1024
#define DIM    128
#define HID    128
#define FUT    128
#define BTILE  4
#define NBLOCKS (BATCH / BTILE)   // 256 -> one block per CU
#define NTHREADS 512
#define LSTR   136                // bf16 elems per LDS row (16B-aligned stride)

typedef __bf16 bf16x8 __attribute__((ext_vector_type(8)));
typedef float  f32x4  __attribute__((ext_vector_type(4)));
typedef unsigned int uint32x2 __attribute__((ext_vector_type(2)));

#define LOG2E 1.4426950408889634f

#if defined(__has_builtin)
#if __has_builtin(__builtin_amdgcn_permlane16_swap) && __has_builtin(__builtin_amdgcn_permlane32_swap)
#define HAVE_PERMSWAP 1
#endif
#endif
#ifndef HAVE_PERMSWAP
#define HAVE_PERMSWAP 0
#endif

// W'/b' stash: module-scope device globals (code-object data section).
// Not part of any harness buffer -> no overflow (round-8 lesson: d_ws is too
// small) and no aliasing with out (round-9 lesson: stash-in-out races with
// tf=0 writes across blocks). Rewritten by prep_wfut every launch
// (replay-idempotent); same-stream kernel ordering makes it visible to
// lstm_forecast.
__device__ __bf16 g_wfut[4 * HID * HID];   // W' = W_hh + W_ih@W_lin  (bf16)
__device__ float  g_wfutb[4 * HID];        // b' = b_ih+b_hh+W_ih@b_lin

// load 8 consecutive fp32, convert (RNE) to a bf16x8 MFMA fragment
__device__ __forceinline__ bf16x8 ldfrag(const float* __restrict__ p) {
    f32x4 a = *(const f32x4*)p;
    f32x4 b = *(const f32x4*)(p + 4);
    bf16x8 r;
    r[0] = (__bf16)a[0]; r[1] = (__bf16)a[1]; r[2] = (__bf16)a[2]; r[3] = (__bf16)a[3];
    r[4] = (__bf16)b[0]; r[5] = (__bf16)b[1]; r[6] = (__bf16)b[2]; r[7] = (__bf16)b[3];
    return r;
}

__device__ __forceinline__ bf16x8 zfrag() {
    bf16x8 r;
    #pragma unroll
    for (int i = 0; i < 8; ++i) r[i] = (__bf16)0.0f;
    return r;
}

// one LSTM cell update from gate preacts {i,f,g,o}; c updated in place.
__device__ __forceinline__ float cell_update(f32x4 gv, float& c) {
    float pi = gv[0], pf = gv[1], pg = gv[2], po = gv[3];
    float ti = __builtin_amdgcn_exp2f(-LOG2E        * __builtin_fabsf(pi));
    float tf = __builtin_amdgcn_exp2f(-LOG2E        * __builtin_fabsf(pf));
    float tg = __builtin_amdgcn_exp2f(-2.0f * LOG2E * __builtin_fabsf(pg));
    float to = __builtin_amdgcn_exp2f(-LOG2E        * __builtin_fabsf(po));
    float di = 1.0f + ti, df = 1.0f + tf, dg = 1.0f + tg, dox = 1.0f + to;
    float p1 = di * df, p2 = dg * dox;
    float invP  = __builtin_amdgcn_rcpf(p1 * p2);
    float inv12 = invP * p2;   // 1/(di*df)
    float inv34 = invP * p1;   // 1/(dg*dox)
    float ig = ((pi >= 0.0f) ? 1.0f : ti) * (inv12 * df);
    float fg = ((pf >= 0.0f) ? 1.0f : tf) * (inv12 * di);
    float og = ((po >= 0.0f) ? 1.0f : to) * (inv34 * dg);
    float gg = __builtin_copysignf((1.0f - tg) * (inv34 * dox), pg);
    c = fg * c + ig * gg;
    float tc  = __builtin_amdgcn_exp2f(-2.0f * LOG2E * __builtin_fabsf(c));
    float thc = __builtin_copysignf((1.0f - tc) * __builtin_amdgcn_rcpf(1.0f + tc), c);
    return og * thc;
}

__device__ __forceinline__ float sel4(int q, float b0, float b1, float b2, float b3) {
    float lo = (q & 1) ? b1 : b0;
    float hi = (q & 1) ? b3 : b2;
    return (q & 2) ? hi : lo;
}

#if HAVE_PERMSWAP
// Direction-agnostic permlane gather (probed at runtime). Lane (q,m) ends up
// with acc row (q ^ fmap); ownership absorbs the XOR via rb = q ^ fmap.
__device__ __forceinline__ float gate_gather_perm(f32x4 a, bool r1_16, bool r1_32) {
    uint32x2 s01 = __builtin_amdgcn_permlane16_swap(__float_as_uint(a[0]), __float_as_uint(a[1]), false, false);
    uint32x2 s23 = __builtin_amdgcn_permlane16_swap(__float_as_uint(a[2]), __float_as_uint(a[3]), false, false);
    unsigned lo = r1_16 ? s01[1] : s01[0];
    unsigned hi = r1_16 ? s23[1] : s23[0];
    uint32x2 fin = __builtin_amdgcn_permlane32_swap(lo, hi, false, false);
    return __uint_as_float(r1_32 ? fin[1] : fin[0]);
}
#endif

// ---------- prep kernel: W' = W_hh + W_ih @ W_lin ; b' = b_ih+b_hh+W_ih@b_lin ----------
// grid 128 x 512: block covers 4 rows n of W' (512x128), one output per thread.
// Writes the device-global stash.
__global__ __launch_bounds__(512)
void prep_wfut(const float* __restrict__ W_ih, const float* __restrict__ W_hh,
               const float* __restrict__ b_ih, const float* __restrict__ b_hh,
               const float* __restrict__ W_lin, const float* __restrict__ b_lin)
{
    __shared__ float wl[64 * 128];   // half of W_lin (f32, 32 KB)
    __shared__ float sc[512];
    const int tid = threadIdx.x;
    const int r = tid >> 7, k = tid & 127;
    const int n = blockIdx.x * 4 + r;

    float acc = W_hh[(size_t)n * HID + k];
    #pragma unroll
    for (int half = 0; half < 2; ++half) {
        __syncthreads();
        for (int i = tid; i < 64 * 128; i += 512)
            wl[i] = W_lin[half * 64 * 128 + i];
        __syncthreads();
        #pragma unroll 8
        for (int d = 0; d < 64; ++d)
            acc += W_ih[(size_t)n * DIM + half * 64 + d] * wl[d * 128 + k];
    }
    g_wfut[(size_t)n * HID + k] = (__bf16)acc;

    // b' reduction: sum_d W_ih[n][d] * b_lin[d], 128 lanes per n
    sc[tid] = W_ih[(size_t)n * DIM + k] * b_lin[k];
    __syncthreads();
    for (int s = 64; s > 0; s >>= 1) {
        if (k < s) sc[r * 128 + k] += sc[r * 128 + k + s];
        __syncthreads();
    }
    if (k == 0) g_wfutb[n] = b_ih[n] + b_hh[n] + sc[r * 128];
}

// ---------- main kernel ----------
__global__ __launch_bounds__(NTHREADS, 2)
void lstm_forecast(const float* __restrict__ inp,
                   const float* __restrict__ W_ih, const float* __restrict__ W_hh,
                   const float* __restrict__ b_ih, const float* __restrict__ b_hh,
                   const float* __restrict__ W_lin, const float* __restrict__ b_lin,
                   float* __restrict__ out)
{
    // h: double-buffered (bf16), rows 4..15 stay zero (never read: masked).
    // x_sh: 16-row tile = 4 timesteps x 4 batch rows (row = 4*(b^fmap) + t'),
    //       restaged once per 4 steps. Future phase uses no x at all.
    __shared__ __bf16 x_sh[16 * LSTR];
    __shared__ __bf16 h_sh[2][16 * LSTR];

    const int tid  = threadIdx.x;
    const int lane = tid & 63;
    const int wave = tid >> 6;      // 0..7
    const int q    = lane >> 4;     // 0..3
    const int m    = lane & 15;     // 0..15
    const int bo   = blockIdx.x * BTILE;

    for (int i = tid; i < 16 * LSTR; i += NTHREADS) {
        x_sh[i] = (__bf16)0.0f;
        h_sh[0][i] = (__bf16)0.0f;
        h_sh[1][i] = (__bf16)0.0f;
    }

    // ---- runtime probe of the permlane-swap convention ----
    bool use_perm = false, r1_16 = false, r1_32 = false;
    int  fmap = 0;
#if HAVE_PERMSWAP
    {
        unsigned lid = (unsigned)lane;
        uint32x2 t16 = __builtin_amdgcn_permlane16_swap(lid, lid + 1000u, false, false);
        unsigned v16 = (unsigned)__builtin_amdgcn_readlane((int)t16[0], 0);
        uint32x2 t32 = __builtin_amdgcn_permlane32_swap(lid, lid + 1000u, false, false);
        unsigned v32 = (unsigned)__builtin_amdgcn_readlane((int)t32[0], 0);
        bool ok16 = (v16 == 0u) || (v16 == 16u) || (v16 == 1000u) || (v16 == 1016u);
        bool ok32 = (v32 == 0u) || (v32 == 32u) || (v32 == 1000u) || (v32 == 1032u);
        r1_16 = (v16 == 16u) || (v16 == 1016u);
        r1_32 = (v32 == 32u) || (v32 == 1032u);
        bool fl16 = (v16 >= 1000u);
        bool fl32 = (v32 >= 1000u);
        use_perm = ok16 && ok32;
        fmap = (fl16 ? 1 : 0) | (fl32 ? 2 : 0);
    }
#endif

    // ---- persistent weight fragments in VGPRs ----
    bf16x8 wih[4][4], whh[4][4], wlin[4];
    float  bias_g[4];
    #pragma unroll
    for (int g = 0; g < 4; ++g) {
        const int n = g * HID + wave * 16 + m;
        bias_g[g] = b_ih[n] + b_hh[n];
        #pragma unroll
        for (int kt = 0; kt < 4; ++kt) {
            wih[g][kt] = ldfrag(W_ih + (size_t)n * DIM + kt * 32 + q * 8);
            whh[g][kt] = ldfrag(W_hh + (size_t)n * HID + kt * 32 + q * 8);
        }
    }
    const int   nl     = wave * 16 + m;
    const float bias_l = b_lin[nl];
    #pragma unroll
    for (int kt = 0; kt < 4; ++kt)
        wlin[kt] = ldfrag(W_lin + (size_t)nl * HID + kt * 32 + q * 8);

    // cell ownership: lane (q,m) owns (batch row rb, hidden col jj)
    const int rb = use_perm ? (q ^ fmap) : q;
    const int jj = wave * 16 + m;
    float creg = 0.0f;

    const int lk    = m * LSTR + q * 8;     // A-frag base offset (bf16 elems)
    const int paddr = (lane & 15) << 2;     // ds_bpermute byte addr

    // x staging ownership: thread loads inp[t][bo+cr][cc]
    const int cr = tid >> 7, cc = tid & 127;
    const float* xptr = inp + (size_t)(bo + cr) * DIM + cc;
    const size_t XS = (size_t)BATCH * DIM;
    // x-tile row base for this thread's batch row (XOR matches gather remap)
    const int xrowb = 4 * (use_perm ? (cr ^ fmap) : cr);

    // two register banks of 8 timesteps each
    float bank0[8], bank1[8];
    #pragma unroll
    for (int k = 0; k < 8; ++k) {
        bank0[k] = xptr[(size_t)k * XS];
        bank1[k] = xptr[(size_t)(8 + k) * XS];
    }

    __syncthreads();

    // per-4-step group: xacc[g] reg j = bias + xW for (batch rb, step t'=j)
    f32x4 xacc[4];

    // ================= main recurrence =================
    for (int tb = 0; tb < TSTEPS; tb += 16) {
        #pragma unroll
        for (int j = 0; j < 16; ++j) {
            const int p = j & 1;
            if ((j & 3) == 0) {
                // stage 16-row x tile for steps tb+j .. tb+j+3
                #pragma unroll
                for (int k = 0; k < 4; ++k) {
                    float xv = ((j + k) < 8) ? bank0[j + k] : bank1[j + k - 8];
                    x_sh[(xrowb + k) * LSTR + cc] = (__bf16)xv;
                }
            }
            __syncthreads();   // x tile (group start) + h_t visible

            if (j == 7) {
                if (tb + 16 < TSTEPS) {
                    #pragma unroll
                    for (int k = 0; k < 8; ++k)
                        bank0[k] = xptr[(size_t)(tb + 16 + k) * XS];
                }
            }
            if (j == 15) {
                if (tb + 24 < TSTEPS) {
                    #pragma unroll
                    for (int k = 0; k < 8; ++k)
                        bank1[k] = xptr[(size_t)(tb + 24 + k) * XS];
                }
            }

            if ((j & 3) == 0) {
                // group-start: bias + x@W_ih for 4 steps at full 16-row
                // MFMA utilization (amortized 4 MFMA/step)
                #pragma unroll
                for (int g = 0; g < 4; ++g)
                    xacc[g] = (f32x4){bias_g[g], bias_g[g], bias_g[g], bias_g[g]};
                #pragma unroll
                for (int kt = 0; kt < 4; ++kt) {
                    bf16x8 ax = *(const bf16x8*)&x_sh[lk + kt * 32];
                    #pragma unroll
                    for (int g = 0; g < 4; ++g)
                        xacc[g] = __builtin_amdgcn_mfma_f32_16x16x32_bf16(ax, wih[g][kt], xacc[g], 0, 0, 0);
                }
            }

            // recurrent part: h @ W_hh only. Rows m>=4 of the A-tile are
            // known-zero: skip their LDS read entirely (exec-masked) and
            // feed a zero fragment -> 4x less LDS traffic on the h burst.
            f32x4 hacc[4];
            #pragma unroll
            for (int g = 0; g < 4; ++g)
                hacc[g] = (f32x4){0.0f, 0.0f, 0.0f, 0.0f};
            #pragma unroll
            for (int kt = 0; kt < 4; ++kt) {
                bf16x8 ah = zfrag();
                if (m < BTILE) ah = *(const bf16x8*)&h_sh[p][lk + kt * 32];
                #pragma unroll
                for (int g = 0; g < 4; ++g)
                    hacc[g] = __builtin_amdgcn_mfma_f32_16x16x32_bf16(ah, whh[g][kt], hacc[g], 0, 0, 0);
            }

            f32x4 gv;
#if HAVE_PERMSWAP
            if (use_perm) {
                #pragma unroll
                for (int g = 0; g < 4; ++g)
                    gv[g] = gate_gather_perm(hacc[g], r1_16, r1_32) + xacc[g][j & 3];
            } else
#endif
            {
                #pragma unroll
                for (int g = 0; g < 4; ++g) {
                    float b0 = __int_as_float(__builtin_amdgcn_ds_bpermute(paddr, __float_as_int(hacc[g][0])));
                    float b1 = __int_as_float(__builtin_amdgcn_ds_bpermute(paddr, __float_as_int(hacc[g][1])));
                    float b2 = __int_as_float(__builtin_amdgcn_ds_bpermute(paddr, __float_as_int(hacc[g][2])));
                    float b3 = __int_as_float(__builtin_amdgcn_ds_bpermute(paddr, __float_as_int(hacc[g][3])));
                    gv[g] = sel4(q, b0, b1, b2, b3) + xacc[g][j & 3];
                }
            }

            float h = cell_update(gv, creg);
            h_sh[p ^ 1][rb * LSTR + jj] = (__bf16)h;   // for step t+1
        }
    }

    // ================= future phase (folded recurrence) =================
    // gates_t = h_t @ W'^T + b'  with  W' = W_hh + W_ih@W_lin (prep kernel),
    // so the o -> x feedback disappears: one barrier, 20 MFMAs per step.
    bf16x8 wfut[4][4];
    float  bias_f[4];
    #pragma unroll
    for (int g = 0; g < 4; ++g) {
        const int n = g * HID + nl;
        bias_f[g] = g_wfutb[n];
        #pragma unroll
        for (int kt = 0; kt < 4; ++kt)
            wfut[g][kt] = *(const bf16x8*)(g_wfut + (size_t)n * HID + kt * 32 + q * 8);
    }

    int ph = 0;   // h_512 is in h_sh[0]
    for (int tf = 0; tf <= FUT; ++tf) {
        __syncthreads();   // h_sh[ph] visible
        bf16x8 ahf[4];
        #pragma unroll
        for (int kt = 0; kt < 4; ++kt) {
            ahf[kt] = zfrag();
            if (m < BTILE) ahf[kt] = *(const bf16x8*)&h_sh[ph][lk + kt * 32];
        }

        f32x4 accl = (f32x4){bias_l, bias_l, bias_l, bias_l};
        #pragma unroll
        for (int kt = 0; kt < 4; ++kt)
            accl = __builtin_amdgcn_mfma_f32_16x16x32_bf16(ahf[kt], wlin[kt], accl, 0, 0, 0);
        if (q == 0) {
            #pragma unroll
            for (int r = 0; r < 4; ++r)
                out[(size_t)tf * BATCH * HID + (size_t)(bo + r) * HID + nl] = accl[r];
        }
        if (tf == FUT) break;

        f32x4 facc[4];
        #pragma unroll
        for (int g = 0; g < 4; ++g)
            facc[g] = (f32x4){bias_f[g], bias_f[g], bias_f[g], bias_f[g]};
        #pragma unroll
        for (int kt = 0; kt < 4; ++kt) {
            #pragma unroll
            for (int g = 0; g < 4; ++g)
                facc[g] = __builtin_amdgcn_mfma_f32_16x16x32_bf16(ahf[kt], wfut[g][kt], facc[g], 0, 0, 0);
        }

        f32x4 gv;
#if HAVE_PERMSWAP
        if (use_perm) {
            #pragma unroll
            for (int g = 0; g < 4; ++g)
                gv[g] = gate_gather_perm(facc[g], r1_16, r1_32);
        } else
#endif
        {
            #pragma unroll
            for (int g = 0; g < 4; ++g) {
                float b0 = __int_as_float(__builtin_amdgcn_ds_bpermute(paddr, __float_as_int(facc[g][0])));
                float b1 = __int_as_float(__builtin_amdgcn_ds_bpermute(paddr, __float_as_int(facc[g][1])));
                float b2 = __int_as_float(__builtin_amdgcn_ds_bpermute(paddr, __float_as_int(facc[g][2])));
                float b3 = __int_as_float(__builtin_amdgcn_ds_bpermute(paddr, __float_as_int(facc[g][3])));
                gv[g] = sel4(q, b0, b1, b2, b3);
            }
        }

        float h = cell_update(gv, creg);
        h_sh[ph ^ 1][rb * LSTR + jj] = (__bf16)h;
        ph ^= 1;
    }
}

extern "C" void kernel_launch(void* const* d_in, const int* in_sizes, int n_in,
                              void* d_out, int out_size, void* d_ws, size_t ws_size,
                              hipStream_t stream) {
    const float* inp   = (const float*)d_in[0];
    const float* W_ih  = (const float*)d_in[1];
    const float* W_hh  = (const float*)d_in[2];
    const float* b_ih  = (const float*)d_in[3];
    const float* b_hh  = (const float*)d_in[4];
    const float* W_lin = (const float*)d_in[5];
    const float* b_lin = (const float*)d_in[6];
    float* out = (float*)d_out;

    hipLaunchKernelGGL(prep_wfut, dim3(128), dim3(512), 0, stream,
                       W_ih, W_hh, b_ih, b_hh, W_lin, b_lin);
    hipLaunchKernelGGL(lstm_forecast, dim3(NBLOCKS), dim3(NTHREADS), 0, stream,
                       inp, W_ih, W_hh, b_ih, b_hh, W_lin, b_lin, out);
}